// Round 18
// baseline (240.639 us; speedup 1.0000x reference)
//
#include <hip/hip_runtime.h>
#include <hip/hip_bf16.h>
#include <math.h>

#define B_    4
#define CIN_  256
#define COUT_ 256
#define H_    128
#define W_    128
#define HW_   16384
#define SD_   512
#define HO_   130
#define HU_   260
#define NT_   12

typedef unsigned short ushort_t;
typedef __attribute__((ext_vector_type(8))) short short8;
typedef __attribute__((ext_vector_type(4))) float f32x4;
typedef __attribute__((ext_vector_type(2))) float f32x2;

__device__ inline ushort_t f2bf_(float v) {
  union { float f; unsigned u; } x; x.f = v;
  unsigned r = x.u + 0x7fffu + ((x.u >> 16) & 1u);
  return (ushort_t)(r >> 16);
}
__device__ inline void gll16(const ushort_t* g, ushort_t* l) {
  __builtin_amdgcn_global_load_lds(
      (const __attribute__((address_space(1))) unsigned int*)g,
      (__attribute__((address_space(3))) unsigned int*)l, 16, 0, 0);
}

// ---------------- K1: modulation s[b][cin] ----------------
__global__ __launch_bounds__(256) void k_mod(const float* __restrict__ style,
                                             const float* __restrict__ mw,
                                             const float* __restrict__ mb,
                                             float* __restrict__ s) {
  int wid  = (blockIdx.x * blockDim.x + threadIdx.x) >> 6;
  int lane = threadIdx.x & 63;
  int b = wid >> 8, ci = wid & 255;
  const float* st = style + b * SD_;
  const float* w  = mw + ci * SD_;
  float acc = 0.f;
  for (int k = lane; k < SD_; k += 64) acc += st[k] * w[k];
  for (int off = 32; off; off >>= 1) acc += __shfl_down(acc, off);
  if (lane == 0) s[wid] = acc * 0.044194173824159216f + mb[ci];
}

// ---------------- K2: demod[b][cout] ----------------
__global__ __launch_bounds__(256) void k_demod(const float* __restrict__ weight,
                                               const float* __restrict__ s,
                                               float* __restrict__ demod) {
  int wid  = (blockIdx.x * blockDim.x + threadIdx.x) >> 6;
  int lane = threadIdx.x & 63;
  int b = wid >> 8, co = wid & 255;
  const float* wrow = weight + co * CIN_ * 9;
  const float* sb   = s + b * CIN_;
  float acc = 0.f;
  for (int e = lane; e < CIN_ * 9; e += 64) {
    float p = wrow[e] * sb[e / 9];
    acc += p * p;
  }
  for (int off = 32; off; off >>= 1) acc += __shfl_down(acc, off);
  if (lane == 0) demod[wid] = rsqrtf(acc + 1e-8f);
}

// ---------------- K2b: weight pre-transform (bf16) ----------------
__global__ __launch_bounds__(256) void k_prep_w(const float* __restrict__ W,
                                                ushort_t* __restrict__ Wth) {
  int idx = blockIdx.x * 256 + threadIdx.x;
  if (idx >= 589824) return;
  int j  = idx & 7;
  int co = (idx >> 3) & 127;
  int kc = (idx >> 10) & 3;
  int kb = (idx >> 12) & 7;
  int cb = (idx >> 15) & 1;
  int t  = idx >> 16;
  int ci  = kb * 32 + kc * 8 + j;
  int cog = cb * 128 + co;
  Wth[idx] = f2bf_(W[(cog * CIN_ + ci) * 9 + t]);
}

// ---------------- K2c: X pre-transform (pure bf16) ----------------
__global__ __launch_bounds__(256) void k_prep_x(const float* __restrict__ input,
                                                const float* __restrict__ s,
                                                ushort_t* __restrict__ Xt,
                                                float* __restrict__ zp) {
  int b = blockIdx.z, cb = blockIdx.y, px0 = blockIdx.x * 64;
  int tid = threadIdx.x;
  __shared__ float T[64 * 131];
  __shared__ float sSh[128];
  if (tid < 128) sSh[tid] = s[b * 256 + cb * 128 + tid];
  if (blockIdx.x == 0 && blockIdx.y == 0 && blockIdx.z == 0 && tid < 4)
    zp[tid] = 0.f;
  __syncthreads();
  const float* inb = input + (size_t)(b * 256 + cb * 128) * HW_ + px0;
#pragma unroll
  for (int r2 = 0; r2 < 32; ++r2) {
    int idx = r2 * 256 + tid;
    int ci = idx >> 6, p = idx & 63;
    T[p * 131 + ci] = inb[(size_t)ci * HW_ + p] * sSh[ci];
  }
  __syncthreads();
  ushort_t* xb = Xt + (size_t)b * HW_ * 256 + cb * 128;
#pragma unroll
  for (int r2 = 0; r2 < 16; ++r2) {
    int u = r2 * 256 + tid;
    int cp = u & 63, p = u >> 6;
    float v0 = T[p * 131 + 2 * cp], v1 = T[p * 131 + 2 * cp + 1];
    unsigned pk = (unsigned)f2bf_(v0) | ((unsigned)f2bf_(v1) << 16);
    *(unsigned*)(xb + ((size_t)(px0 + p)) * 256 + cp * 2) = pk;
  }
}

// ---------------- K3: modulated conv via MFMA (unchanged from R16) ----------------
#define XCELLS 864
#define XROUNDS 4
#define XBUFU  1024

__global__ __launch_bounds__(256, 3) void k_conv_mfma(
    const ushort_t* __restrict__ Xt, const ushort_t* __restrict__ Wth,
    const float* __restrict__ demod, const float* __restrict__ bias,
    const ushort_t* __restrict__ zpg, float* __restrict__ out1) {
  const int tid = threadIdx.x;
  const int b = blockIdx.z >> 1, cb = blockIdx.z & 1;
  const int y0 = blockIdx.y * 10, x0 = blockIdx.x * 16;
  const int lane = tid & 63, lr = lane & 15, kcc = lane >> 4;
  const int w = tid >> 6;

  __shared__ __align__(16) ushort_t XL[2][XBUFU * 8];

  f32x4 acc[2][10];
#pragma unroll
  for (int i = 0; i < 2; ++i)
#pragma unroll
    for (int jj = 0; jj < 10; ++jj) acc[i][jj] = (f32x4)0.f;

  const ushort_t* gsrc[XROUNDS];
  bool okr[XROUNDS];
#pragma unroll
  for (int r = 0; r < XROUNDS; ++r) {
    int u = r * 256 + tid;
    const ushort_t* p = zpg;
    bool ok = false;
    if (u < XCELLS) {
      int kc = u / 216, cell = u - kc * 216;
      int hy = cell / 18, hx = cell - hy * 18;
      int iy = y0 + hy - 2, ix = x0 + hx - 2;
      if ((unsigned)iy < 128u && (unsigned)ix < 128u) {
        p = Xt + (((size_t)b * HW_ + iy * W_ + ix) << 8) + kc * 8;
        ok = true;
      }
    }
    gsrc[r] = p; okr[r] = ok;
  }

  auto stage = [&](int kb, int bufsel) {
    ushort_t* lb = &XL[bufsel][(size_t)tid * 8];
#pragma unroll
    for (int r = 0; r < XROUNDS; ++r) {
      const ushort_t* g = okr[r] ? gsrc[r] + kb * 32 : zpg;
      gll16(g, lb + r * 2048);
    }
  };

  stage(0, 0);
  __syncthreads();

  for (int kb = 0; kb < 8; ++kb) {
    const ushort_t* Xc = &XL[kb & 1][0];
    const int wbo = cb * 32768 + kb * 4096 + kcc * 1024 + (w * 32 + lr) * 8;
#pragma unroll
    for (int kx = 0; kx < 3; ++kx) {
      short8 ah[3][2];
#pragma unroll
      for (int ky = 0; ky < 3; ++ky) {
        const ushort_t* wh = Wth + wbo + (ky * 3 + kx) * 65536;
        ah[ky][0] = *(const short8*)wh;
        ah[ky][1] = *(const short8*)(wh + 128);
      }
      if (kx == 0) {
        __builtin_amdgcn_sched_barrier(0);
        if (kb < 7) stage(kb + 1, (kb & 1) ^ 1);
      }
#pragma unroll
      for (int r = 0; r < 12; ++r) {
        const int c16 = (kcc * 216 + r * 18 + lr + kx) * 8;
        short8 bh = *(const short8*)&Xc[c16];
#pragma unroll
        for (int ky = 0; ky < 3; ++ky) {
          const int bn = r - ky;
          if (bn >= 0 && bn < 10) {
            acc[0][bn] = __builtin_amdgcn_mfma_f32_16x16x32_bf16(ah[ky][0], bh, acc[0][bn], 0, 0, 0);
            acc[1][bn] = __builtin_amdgcn_mfma_f32_16x16x32_bf16(ah[ky][1], bh, acc[1][bn], 0, 0, 0);
          }
        }
      }
    }
    if (kb < 7) __syncthreads();
  }

#pragma unroll
  for (int am = 0; am < 2; ++am) {
#pragma unroll
    for (int r = 0; r < 4; ++r) {
      int cog = cb * 128 + w * 32 + am * 16 + kcc * 4 + r;
      float dm = demod[b * 256 + cog];
      float bv = bias[cog];
      int ox = x0 + lr;
      if (ox < HO_) {
#pragma unroll
        for (int bn = 0; bn < 10; ++bn) {
          int oy = y0 + bn;
          out1[((b * 256 + cog) * HO_ + oy) * HO_ + ox] = acc[am][bn][r] * dm + bv;
        }
      }
    }
  }
}

// ---------------- K4: fused FIR (R18: 2 planes/block as packed f32x2) ----------------
#define I1S 132
#define I2S 260

__global__ __launch_bounds__(256) void k_fir(const float* __restrict__ src,
                                             const float* __restrict__ upf,
                                             const float* __restrict__ dnf,
                                             float* __restrict__ dst) {
  const int pp = blockIdx.y;              // plane pair: planes 2pp, 2pp+1
  const int y0 = blockIdx.x * 8;
  const int tid = threadIdx.x;

  __shared__ __align__(16) f32x2 I1D[26 * I1S];   // I1 (P1->P2), then D 8x272 (P3->P4)
  __shared__ __align__(16) f32x2 B2[26 * I2S];    // SD 18x132 (P0->P1), then I2 (P2->P3)

  f32x2* SD = B2;
  f32x2* I2 = B2;
  f32x2* I1 = I1D;
  f32x2* D  = I1D;

  float fe[6], fo[6], fdt[12];
#pragma unroll
  for (int j = 0; j < 6; ++j) { fe[j] = upf[2 * j] * 2.f; fo[j] = upf[2 * j + 1] * 2.f; }
#pragma unroll
  for (int t = 0; t < NT_; ++t) fdt[t] = dnf[t];
  const float kPos = 1.41421356237309515f, kNeg = 0.28284271247461903f;

  auto lrc = [&](f32x2 a) {
    float x = a.x, y = a.y;
    x *= (x >= 0.f) ? kPos : kNeg;
    y *= (y >= 0.f) ? kPos : kNeg;
    x = fminf(fmaxf(x, -256.f), 256.f);
    y = fminf(fmaxf(y, -256.f), 256.f);
    return (f32x2){x, y};
  };

  // ---- P0: stage src rows [y0-5, y0+13) for both planes ----
  const float* sp0 = src + (size_t)(2 * pp) * (HO_ * HO_);
  const float* sp1 = sp0 + HO_ * HO_;
#pragma unroll
  for (int k = 0; k < 3; ++k) {
    int idx = tid + k * 256;
    if (idx < 594) {
      int r = idx / 33, q = idx - 33 * r;
      int gy = y0 - 5 + r;
      int cbase = 4 * q;
      float4 a = make_float4(0.f, 0.f, 0.f, 0.f);
      float4 b = a;
      if ((unsigned)gy < (unsigned)HO_) {
        const float* r0 = sp0 + gy * HO_ + cbase;
        const float* r1 = sp1 + gy * HO_ + cbase;
        a.x = r0[0];                       b.x = r1[0];
        if (cbase + 1 < HO_) { a.y = r0[1]; b.y = r1[1]; }
        if (cbase + 2 < HO_) { a.z = r0[2]; b.z = r1[2]; }
        if (cbase + 3 < HO_) { a.w = r0[3]; b.w = r1[3]; }
      }
      f32x2* d = &SD[r * 132 + cbase];
      d[0] = (f32x2){a.x, b.x};
      d[1] = (f32x2){a.y, b.y};
      d[2] = (f32x2){a.z, b.z};
      d[3] = (f32x2){a.w, b.w};
    }
  }
  __syncthreads();

  // ---- P1: vertical up-FIR -> I1[u][c] ----
  {
    int c = tid & 127, uh = tid >> 7;
    f32x2 wv[6];
    if (uh == 0) {
#pragma unroll
      for (int j = 0; j < 6; ++j) wv[j] = SD[j * 132 + c];
#pragma unroll
      for (int lr = 0; lr < 7; ++lr) {
        f32x2 a = fo[0]*wv[0] + fo[1]*wv[1] + fo[2]*wv[2] + fo[3]*wv[3] + fo[4]*wv[4] + fo[5]*wv[5];
        int ugl = 2 * y0 - 5 + 2 * lr;
        I1[(2 * lr) * I1S + c] = ((unsigned)ugl < (unsigned)HU_) ? a : (f32x2)0.f;
        if (lr < 6) {
#pragma unroll
          for (int j = 0; j < 5; ++j) wv[j] = wv[j + 1];
          wv[5] = SD[(lr + 6) * 132 + c];
        }
      }
#pragma unroll
      for (int j = 0; j < 6; ++j) wv[j] = SD[j * 132 + c];
#pragma unroll
      for (int lr = 0; lr < 6; ++lr) {
        f32x2 a = fe[0]*wv[0] + fe[1]*wv[1] + fe[2]*wv[2] + fe[3]*wv[3] + fe[4]*wv[4] + fe[5]*wv[5];
        int ugl = 2 * y0 - 4 + 2 * lr;
        I1[(2 * lr + 1) * I1S + c] = ((unsigned)ugl < (unsigned)HU_) ? a : (f32x2)0.f;
        if (lr < 5) {
#pragma unroll
          for (int j = 0; j < 5; ++j) wv[j] = wv[j + 1];
          wv[5] = SD[(lr + 6) * 132 + c];
        }
      }
    } else {
#pragma unroll
      for (int j = 0; j < 6; ++j) wv[j] = SD[(6 + j) * 132 + c];
#pragma unroll
      for (int lr = 6; lr < 13; ++lr) {
        f32x2 a = fe[0]*wv[0] + fe[1]*wv[1] + fe[2]*wv[2] + fe[3]*wv[3] + fe[4]*wv[4] + fe[5]*wv[5];
        int ugl = 2 * y0 - 4 + 2 * lr;
        I1[(2 * lr + 1) * I1S + c] = ((unsigned)ugl < (unsigned)HU_) ? a : (f32x2)0.f;
        if (lr < 12) {
#pragma unroll
          for (int j = 0; j < 5; ++j) wv[j] = wv[j + 1];
          wv[5] = SD[(lr + 6) * 132 + c];
        }
      }
#pragma unroll
      for (int j = 0; j < 6; ++j) wv[j] = SD[(7 + j) * 132 + c];
#pragma unroll
      for (int lr = 7; lr < 13; ++lr) {
        f32x2 a = fo[0]*wv[0] + fo[1]*wv[1] + fo[2]*wv[2] + fo[3]*wv[3] + fo[4]*wv[4] + fo[5]*wv[5];
        int ugl = 2 * y0 - 5 + 2 * lr;
        I1[(2 * lr) * I1S + c] = ((unsigned)ugl < (unsigned)HU_) ? a : (f32x2)0.f;
        if (lr < 12) {
#pragma unroll
          for (int j = 0; j < 5; ++j) wv[j] = wv[j + 1];
          wv[5] = SD[(lr + 6) * 132 + c];
        }
      }
    }
    if (tid >= 200 && tid < 252) {
      int t2 = tid - 200;
      int c2 = 128 + (t2 & 1), u2 = t2 >> 1;
      f32x2 a = (f32x2)0.f;
      if ((u2 & 1) == 0) {
        int lr = u2 >> 1;
#pragma unroll
        for (int j = 0; j < 6; ++j) a += fo[j] * SD[(lr + j) * 132 + c2];
      } else {
        int lr = (u2 - 1) >> 1;
#pragma unroll
        for (int j = 0; j < 6; ++j) a += fe[j] * SD[(lr + j) * 132 + c2];
      }
      int ugl = 2 * y0 - 5 + u2;
      I1[u2 * I1S + c2] = ((unsigned)ugl < (unsigned)HU_) ? a : (f32x2)0.f;
    }
    if (tid < 52) {
      int r = tid >> 1, col = 130 + (tid & 1);
      I1[r * I1S + col] = (f32x2)0.f;
    }
  }
  __syncthreads();

  // ---- P2: horizontal up-FIR + lrelu + clamp -> I2[u][v] ----
  auto ld2 = [&](const f32x2* p, f32x2& a, f32x2& b) {
    f32x4 t = *(const f32x4*)p;
    a = (f32x2){t.x, t.y};
    b = (f32x2){t.z, t.w};
  };
  for (int idx = tid; idx < 26 * 33; idx += 256) {
    int s = idx / 26, u = idx - 26 * s;
    const f32x2* I1r = &I1[u * I1S];
    if (s < 32) {
      f32x2 w12[12];
      if (s == 0) {
        w12[0] = w12[1] = w12[2] = w12[3] = (f32x2)0.f;
        ld2(&I1r[0], w12[4], w12[5]);
        ld2(&I1r[2], w12[6], w12[7]);
        ld2(&I1r[4], w12[8], w12[9]);
        ld2(&I1r[6], w12[10], w12[11]);
      } else {
        int c0 = 4 * s;
#pragma unroll
        for (int h = 0; h < 6; ++h)
          ld2(&I1r[c0 - 4 + 2 * h], w12[2 * h], w12[2 * h + 1]);
      }
      f32x2 o[8];
#pragma unroll
      for (int e = 0; e < 4; ++e) {
        o[2*e]   = fe[0]*w12[e+1] + fe[1]*w12[e+2] + fe[2]*w12[e+3] + fe[3]*w12[e+4] + fe[4]*w12[e+5] + fe[5]*w12[e+6];
        o[2*e+1] = fo[0]*w12[e+2] + fo[1]*w12[e+3] + fo[2]*w12[e+4] + fo[3]*w12[e+5] + fo[4]*w12[e+6] + fo[5]*w12[e+7];
      }
#pragma unroll
      for (int e = 0; e < 8; ++e) o[e] = lrc(o[e]);
#pragma unroll
      for (int h = 0; h < 4; ++h)
        *(f32x4*)&I2[u * I2S + 8 * s + 2 * h] =
            (f32x4){o[2*h].x, o[2*h].y, o[2*h+1].x, o[2*h+1].y};
    } else {
      f32x2 w8[8];
      ld2(&I1r[124], w8[0], w8[1]);
      ld2(&I1r[126], w8[2], w8[3]);
      ld2(&I1r[128], w8[4], w8[5]);
      ld2(&I1r[130], w8[6], w8[7]);
      f32x2 q[4];
      q[0] = fe[0]*w8[1] + fe[1]*w8[2] + fe[2]*w8[3] + fe[3]*w8[4] + fe[4]*w8[5] + fe[5]*w8[6];
      q[1] = fo[0]*w8[2] + fo[1]*w8[3] + fo[2]*w8[4] + fo[3]*w8[5] + fo[4]*w8[6] + fo[5]*w8[7];
      q[2] = fe[0]*w8[2] + fe[1]*w8[3] + fe[2]*w8[4] + fe[3]*w8[5] + fe[4]*w8[6] + fe[5]*w8[7];
      q[3] = fo[0]*w8[3] + fo[1]*w8[4] + fo[2]*w8[5] + fo[3]*w8[6] + fo[4]*w8[7];
#pragma unroll
      for (int e = 0; e < 4; ++e) q[e] = lrc(q[e]);
      *(f32x4*)&I2[u * I2S + 256] = (f32x4){q[0].x, q[0].y, q[1].x, q[1].y};
      *(f32x4*)&I2[u * I2S + 258] = (f32x4){q[2].x, q[2].y, q[3].x, q[3].y};
    }
  }
  __syncthreads();

  // ---- P3: vertical down-FIR -> D[y][v+5] (D overlays dead I1) ----
  {
    if (tid < 96) {
      int r = tid / 12, j = tid - 12 * r;
      int col = (j < 5) ? j : (260 + j);
      D[r * 272 + col] = (f32x2)0.f;
    }
    auto p3col = [&](int v) {
      f32x2 wn[12];
#pragma unroll
      for (int t = 0; t < 12; ++t) wn[t] = I2[t * I2S + v];
#pragma unroll
      for (int y = 0; y < 8; ++y) {
        f32x2 a = (f32x2)0.f;
#pragma unroll
        for (int t = 0; t < 12; ++t) a += fdt[t] * wn[t];
        D[y * 272 + v + 5] = a;
        if (y < 7) {
#pragma unroll
          for (int t = 0; t < 10; ++t) wn[t] = wn[t + 2];
          wn[10] = I2[(2 * y + 12) * I2S + v];
          wn[11] = I2[(2 * y + 13) * I2S + v];
        }
      }
    };
    p3col(tid);
    if (tid < 4) p3col(256 + tid);
  }
  __syncthreads();

  // ---- P4: horizontal down-FIR -> global (both planes) ----
  if (tid < 208) {
    int row = tid / 26, s4 = tid - 26 * row;
    int gy = y0 + row;
    if (gy < HO_) {
      f32x2 wn[20];
#pragma unroll
      for (int k = 0; k < 10; ++k)
        ld2(&D[row * 272 + 10 * s4 + 2 * k], wn[2 * k], wn[2 * k + 1]);
      float* d0 = dst + (size_t)(2 * pp) * (HO_ * HO_) + gy * HO_ + 5 * s4;
      float* d1 = d0 + HO_ * HO_;
#pragma unroll
      for (int q = 0; q < 5; ++q) {
        f32x2 a = (f32x2)0.f;
#pragma unroll
        for (int t = 0; t < 12; ++t) a += fdt[t] * wn[2 * q + t];
        d0[q] = a.x;
        d1[q] = a.y;
      }
    }
  }
}

// ---------------- launch ----------------
extern "C" void kernel_launch(void* const* d_in, const int* in_sizes, int n_in,
                              void* d_out, int out_size, void* d_ws, size_t ws_size,
                              hipStream_t stream) {
  (void)in_sizes; (void)n_in; (void)out_size; (void)ws_size;
  const float* input  = (const float*)d_in[0];
  const float* style  = (const float*)d_in[1];
  const float* weight = (const float*)d_in[2];
  const float* mw     = (const float*)d_in[3];
  const float* mb     = (const float*)d_in[4];
  const float* bias   = (const float*)d_in[5];
  const float* upf    = (const float*)d_in[6];
  const float* dnf    = (const float*)d_in[7];
  float* out = (float*)d_out;

  float* out1   = (float*)d_ws;                               // 69.22 MB
  float* s      = out1 + (size_t)B_ * COUT_ * HO_ * HO_;      // [4][256]
  float* demod  = s + B_ * CIN_;                              // [4][256]
  ushort_t* Wth = (ushort_t*)(demod + B_ * COUT_);            // 1.18 MB
  float*    zp  = (float*)(Wth + 589824);                     // 16 B zero page
  ushort_t* Xt  = (ushort_t*)(zp + 4);                        // 32 MB (bf16)

  k_mod   <<<256, 256, 0, stream>>>(style, mw, mb, s);
  k_prep_x<<<dim3(256, 2, B_), 256, 0, stream>>>(input, s, Xt, zp);
  k_demod <<<256, 256, 0, stream>>>(weight, s, demod);
  k_prep_w<<<2304, 256, 0, stream>>>(weight, Wth);
  k_conv_mfma<<<dim3(9, 13, 8), 256, 0, stream>>>(Xt, Wth, demod, bias,
                                                  (const ushort_t*)zp, out1);
  k_fir   <<<dim3(17, 512), 256, 0, stream>>>(out1, upf, dnf, out);
}